// Round 4
// baseline (46.303 us; speedup 1.0000x reference)
//
#include <hip/hip_runtime.h>
#include <hip/hip_bf16.h>

constexpr int Bc = 4, Cc = 64, Tc = 16, Nc = 256, Hc = 128, Wc = 128;
constexpr int HW  = Hc * Wc;       // 16384
constexpr int THW = Tc * HW;       // 262144
constexpr int NPTS = Bc * Tc * Nc; // 16384

constexpr int QP = 32;                          // points per gather block
constexpr int GATHER_BLOCKS = NPTS / QP;        // 512
constexpr int MSE_BLOCKS    = 64;
constexpr int NSLICE = 232;                     // 64+60+56+52
constexpr int PAIR_BLOCKS = NSLICE * 2;         // 464

// ws float-offset layout:
//   [0..63]       mse partials
//   [64..527]     se partials   (per pair block)
//   [528..991]    cnt partials  (per pair block, as float)
//   [4096..36863]   pcoord: permuted coords, int2 per sorted point (128 KB)
//   [36864..53247]  plabel: permuted labels, int per sorted point (64 KB)
//   [65536..]       sel bf16, sorted order, NPTS x 64 (2 MB)

typedef short short8 __attribute__((ext_vector_type(8)));
typedef float f32x4  __attribute__((ext_vector_type(4)));

__device__ inline unsigned pack_bf16(float a, float b) {
    __hip_bfloat16 ha = __float2bfloat16(a);
    __hip_bfloat16 hb = __float2bfloat16(b);
    unsigned short ua, ub;
    __builtin_memcpy(&ua, &ha, 2);
    __builtin_memcpy(&ub, &hb, 2);
    return (unsigned)ua | ((unsigned)ub << 16);
}

__global__ __launch_bounds__(256) void k1_gather_mse(
        const float* __restrict__ feat,
        const int*   __restrict__ coord,
        const int*   __restrict__ label,
        const float* __restrict__ pred,
        const float* __restrict__ tgt,
        float* __restrict__ ws) {
    __shared__ int   keys[256];
    __shared__ int   ordl[256];
    __shared__ float psum[4][32];
    __shared__ float ls[4];

    int blk = blockIdx.x;
    int t   = threadIdx.x;

    if (blk < GATHER_BLOCKS) {
        int slice = blk >> 3;     // 0..63  (b*16 + t)
        int q     = blk & 7;      // point range q*32 .. q*32+31
        int b     = slice >> 4;
        int tt    = slice & 15;
        int pbase = slice * 256;

        // --- deterministic rank sort by (y,x) ---
        {
            int x = coord[2 * (pbase + t) + 0];
            int y = coord[2 * (pbase + t) + 1];
            int key = (x < 0 || y < 0) ? (1 << 22) : (y * 128 + x);
            keys[t] = key;
            __syncthreads();
            int rank = 0;
            for (int j = 0; j < 256; j++) {
                int kj = keys[j];
                rank += (kj < key || (kj == key && j < t)) ? 1 : 0;
            }
            ordl[rank] = t;
            __syncthreads();
        }

        int wv   = t >> 6;        // channel block wv*16
        int lane = t & 63;
        int pt   = lane & 31;     // 0..31 point within this block's range
        int ch8  = lane >> 5;     // 0/1: which 8-channel half
        int sp   = q * QP + pt;   // sorted position within slice
        int pi   = ordl[sp];      // original index within slice

        int px = coord[2 * (pbase + pi) + 0];
        int py = coord[2 * (pbase + pi) + 1];
        int lb = label[pbase + pi];
        bool ok = (px >= 0) && (py >= 0);

        // permuted coord/label (sorted order) for k2
        if (wv == 0 && ch8 == 0) {
            int* pcoord = (int*)(ws + 4096);
            int* plabel = (int*)(ws + 36864);
            pcoord[2 * (pbase + sp) + 0] = px;
            pcoord[2 * (pbase + sp) + 1] = py;
            plabel[pbase + sp] = lb;
        }

        int axx = ok ? px : 0;
        int ayy = ok ? py : 0;
        const float* fb = feat + (size_t)(b * Cc + wv * 16 + ch8 * 8) * THW
                               + tt * HW + ayy * Wc + axx;
        float v[8];
        #pragma unroll
        for (int j = 0; j < 8; j++) v[j] = fb[(size_t)j * THW];
        if (!ok) {
            #pragma unroll
            for (int j = 0; j < 8; j++) v[j] = 0.0f;
        }
        float sq = 0.0f;
        #pragma unroll
        for (int j = 0; j < 8; j++) sq = fmaf(v[j], v[j], sq);
        sq += __shfl_xor(sq, 32);            // combine the two 8-ch halves
        if (lane < 32) psum[wv][pt] = sq;
        __syncthreads();
        float tot = (psum[0][pt] + psum[1][pt]) + (psum[2][pt] + psum[3][pt]);
        float iv = 1.0f / fmaxf(sqrtf(tot), 1e-12f);

        uint4 o;
        o.x = pack_bf16(v[0] * iv, v[1] * iv);
        o.y = pack_bf16(v[2] * iv, v[3] * iv);
        o.z = pack_bf16(v[4] * iv, v[5] * iv);
        o.w = pack_bf16(v[6] * iv, v[7] * iv);
        char* selBytes = (char*)(ws + 65536);
        uint4* dst = (uint4*)(selBytes + (size_t)(pbase + sp) * 128
                              + (wv * 16 + ch8 * 8) * 2);
        *dst = o;
    } else {
        int i = (blk - GATHER_BLOCKS) * 256 + t;
        float4 p4 = ((const float4*)pred)[i];
        float4 q4 = ((const float4*)tgt)[i];
        float dx = p4.x - q4.x, dy = p4.y - q4.y;
        float dz = p4.z - q4.z, dw = p4.w - q4.w;
        float s = dx * dx + dy * dy + dz * dz + dw * dw;
        #pragma unroll
        for (int o = 32; o; o >>= 1) s += __shfl_xor(s, o);
        if ((t & 63) == 0) ls[t >> 6] = s;
        __syncthreads();
        if (t == 0)
            ws[blk - GATHER_BLOCKS] = (ls[0] + ls[1]) + (ls[2] + ls[3]);
    }
}

__global__ __launch_bounds__(512) void k2_pair(float* __restrict__ ws) {
    const short8* selb   = (const short8*)(ws + 65536);
    const int*    pcoord = (const int*)(ws + 4096);
    const int*    plabel = (const int*)(ws + 36864);

    int blk   = blockIdx.x;
    int slice = blk >> 1;
    int half  = blk & 1;

    int lag, base, thr2;
    if (slice < 64)       { lag = 0; base = 0;   thr2 = 625;  }
    else if (slice < 124) { lag = 1; base = 64;  thr2 = 625;  }
    else if (slice < 180) { lag = 2; base = 124; thr2 = 900;  }
    else                  { lag = 3; base = 180; thr2 = 1225; }
    int idx = slice - base;
    int ns  = Tc - lag;
    int b   = idx / ns;
    int ta  = idx % ns;
    int tb  = ta + lag;
    int pA  = (b * Tc + ta) * Nc;
    int pB  = (b * Tc + tb) * Nc;

    int t    = threadIdx.x;
    int w    = t >> 6;
    int lane = t & 63;
    int lr   = lane & 15;
    int kb   = lane >> 4;   // 0..3

    int rb0 = w * 32;
    int rb1 = w * 32 + 16;

    const short8* arow0 = selb + (size_t)(pA + rb0 + lr) * 8;
    const short8* arow1 = selb + (size_t)(pA + rb1 + lr) * 8;
    short8 a00 = arow0[kb],     a01 = arow0[4 + kb];
    short8 a10 = arow1[kb],     a11 = arow1[4 + kb];

    int ax0[4], ay0[4], la0[4], ax1[4], ay1[4], la1[4];
    #pragma unroll
    for (int i = 0; i < 4; i++) {
        int r0 = pA + rb0 + kb * 4 + i;
        int r1 = pA + rb1 + kb * 4 + i;
        ax0[i] = pcoord[2 * r0]; ay0[i] = pcoord[2 * r0 + 1]; la0[i] = plabel[r0];
        ax1[i] = pcoord[2 * r1]; ay1[i] = pcoord[2 * r1 + 1]; la1[i] = plabel[r1];
    }

    float se = 0.0f;
    int cnt = 0;

    for (int cb = 0; cb < 8; cb++) {
        int m  = half * 128 + cb * 16;
        int pm = pB + m + lr;
        const short8* brow = selb + (size_t)pm * 8;
        short8 b0 = brow[kb], b1 = brow[4 + kb];
        int bx = pcoord[2 * pm], by = pcoord[2 * pm + 1], lb = plabel[pm];
        bool bok = bx >= 0;

        f32x4 acc0 = {0.f, 0.f, 0.f, 0.f};
        acc0 = __builtin_amdgcn_mfma_f32_16x16x32_bf16(a00, b0, acc0, 0, 0, 0);
        acc0 = __builtin_amdgcn_mfma_f32_16x16x32_bf16(a01, b1, acc0, 0, 0, 0);
        #pragma unroll
        for (int i = 0; i < 4; i++) {
            int ddx = ax0[i] - bx, ddy = ay0[i] - by;
            int dd  = ddx * ddx + ddy * ddy;
            bool cond = (dd < thr2) && (ax0[i] >= 0) && bok;
            float lbl = (la0[i] == lb) ? 1.0f : 0.0f;
            float df  = acc0[i] - lbl;
            df = cond ? df : 0.0f;
            se = fmaf(df, df, se);
            cnt += cond ? 1 : 0;
        }

        f32x4 acc1 = {0.f, 0.f, 0.f, 0.f};
        acc1 = __builtin_amdgcn_mfma_f32_16x16x32_bf16(a10, b0, acc1, 0, 0, 0);
        acc1 = __builtin_amdgcn_mfma_f32_16x16x32_bf16(a11, b1, acc1, 0, 0, 0);
        #pragma unroll
        for (int i = 0; i < 4; i++) {
            int ddx = ax1[i] - bx, ddy = ay1[i] - by;
            int dd  = ddx * ddx + ddy * ddy;
            bool cond = (dd < thr2) && (ax1[i] >= 0) && bok;
            float lbl = (la1[i] == lb) ? 1.0f : 0.0f;
            float df  = acc1[i] - lbl;
            df = cond ? df : 0.0f;
            se = fmaf(df, df, se);
            cnt += cond ? 1 : 0;
        }
    }

    #pragma unroll
    for (int o = 32; o; o >>= 1) {
        se  += __shfl_xor(se, o);
        cnt += __shfl_xor(cnt, o);
    }
    __shared__ float wse[8];
    __shared__ int   wcnt[8];
    if (lane == 0) { wse[w] = se; wcnt[w] = cnt; }
    __syncthreads();
    if (t == 0) {
        float S = 0.0f; int C = 0;
        #pragma unroll
        for (int i = 0; i < 8; i++) { S += wse[i]; C += wcnt[i]; }
        ws[64 + blk]  = S;
        ws[528 + blk] = (float)C;
    }
}

__global__ __launch_bounds__(256) void k3_final(
        const float* __restrict__ ws,
        float* __restrict__ out) {
    int t = threadIdx.x;
    int w = t >> 6, lane = t & 63;

    float ms = (t < 64) ? ws[t] : 0.0f;
    float se4[4] = {0, 0, 0, 0};
    float cn4[4] = {0, 0, 0, 0};
    for (int i = t; i < PAIR_BLOCKS; i += 256) {
        int slice = i >> 1;
        int lg = (slice < 64) ? 0 : (slice < 124) ? 1 : (slice < 180) ? 2 : 3;
        se4[lg] += ws[64 + i];
        cn4[lg] += ws[528 + i];
    }
    #pragma unroll
    for (int o = 32; o; o >>= 1) {
        ms += __shfl_xor(ms, o);
        #pragma unroll
        for (int lg = 0; lg < 4; lg++) {
            se4[lg] += __shfl_xor(se4[lg], o);
            cn4[lg] += __shfl_xor(cn4[lg], o);
        }
    }
    __shared__ float sh[4][9];
    if (lane == 0) {
        sh[w][0] = ms;
        #pragma unroll
        for (int lg = 0; lg < 4; lg++) {
            sh[w][1 + lg] = se4[lg];
            sh[w][5 + lg] = cn4[lg];
        }
    }
    __syncthreads();
    if (t == 0) {
        float mse = 0.0f;
        float se[4] = {0, 0, 0, 0}, cn[4] = {0, 0, 0, 0};
        for (int i = 0; i < 4; i++) {
            mse += sh[i][0];
            for (int lg = 0; lg < 4; lg++) {
                se[lg] += sh[i][1 + lg];
                cn[lg] += sh[i][5 + lg];
            }
        }
        float l = 0.0f;
        for (int lg = 0; lg < 4; lg++)
            l += se[lg] / fmaxf(cn[lg], 1.0f);
        out[0] = mse / 65536.0f + 0.25f * l;
    }
}

extern "C" void kernel_launch(void* const* d_in, const int* in_sizes, int n_in,
                              void* d_out, int out_size, void* d_ws, size_t ws_size,
                              hipStream_t stream) {
    const float* predicts = (const float*)d_in[0];
    const float* feature  = (const float*)d_in[1];
    const int*   coord    = (const int*)d_in[2];
    const float* targets  = (const float*)d_in[3];
    const int*   label    = (const int*)d_in[4];
    float* out = (float*)d_out;
    float* ws  = (float*)d_ws;

    hipLaunchKernelGGL(k1_gather_mse, dim3(GATHER_BLOCKS + MSE_BLOCKS), dim3(256),
                       0, stream, feature, coord, label, predicts, targets, ws);
    hipLaunchKernelGGL(k2_pair, dim3(PAIR_BLOCKS), dim3(512), 0, stream, ws);
    hipLaunchKernelGGL(k3_final, dim3(1), dim3(256), 0, stream, ws, out);
}